// Round 10
// baseline (111.416 us; speedup 1.0000x reference)
//
#include <hip/hip_runtime.h>
#include <hip/hip_bf16.h>

#define UNIT_NO 512
#define T_DIM 25
#define K_DIM 20
#define H_DIM 64
#define P_DIM 4096
#define F_DIM 10
#define BATCH 32
#define KTOT (K_DIM * F_DIM)   // 200
#define KPAD 224               // 7 MFMA k-tiles of 32 (Gb tail zeroed)
#define LSTR 232               // Gb row stride (halfwords): 464B -> conflict-free b128 reads
#define FTB_STR 16             // Ftb per-(u,b) stride in halfwords (10 used + 6 pad) = 32B

typedef short bf16x8 __attribute__((ext_vector_type(8)));
typedef float f32x4 __attribute__((ext_vector_type(4)));

__device__ inline unsigned short bf16b(float x) {
    __hip_bfloat16 h = __float2bfloat16(x);   // RNE
    return *(unsigned short*)&h;
}
__device__ inline unsigned int pack2(float lo, float hi) {
    return (unsigned int)bf16b(lo) | ((unsigned int)bf16b(hi) << 16);
}

// Kernel A: per-unit featurize for units [0, Ustar), output bf16.
// Ftb[u][b][16] halfwords (f contiguous, 32B per (u,b), pad zeroed).
// Rounding to bf16 here is numerically identical to rounding at gather time.
__global__ __launch_bounds__(320) void featurize_kernel(
    const float* __restrict__ S, const float* __restrict__ Wf,
    const float* __restrict__ bf, unsigned short* __restrict__ Ftb)
{
    const int u = blockIdx.x;
    __shared__ float Ws[T_DIM * F_DIM];   // [t][f]
    __shared__ float Ss[BATCH * T_DIM];   // [b][t]
    const int tid = threadIdx.x;
    for (int i = tid; i < T_DIM * F_DIM; i += 320)
        Ws[i] = Wf[u * (T_DIM * F_DIM) + i];
    for (int i = tid; i < BATCH * T_DIM; i += 320) {
        int b = i / T_DIM;
        int t = i - b * T_DIM;
        Ss[i] = S[b * (UNIT_NO * T_DIM) + u * T_DIM + t];
    }
    // zero the f-pad [10,16) for all 32 b: 192 slots
    if (tid < 192) {
        int b  = tid / 6;
        int fz = 10 + (tid - b * 6);
        Ftb[(u * BATCH + b) * FTB_STR + fz] = 0;
    }
    __syncthreads();
    const int b = tid / F_DIM;    // 0..31
    const int f = tid - b * F_DIM;
    float acc = 0.f;
#pragma unroll
    for (int t = 0; t < T_DIM; ++t)
        acc = fmaf(Ss[b * T_DIM + t], Ws[t * F_DIM + f], acc);
    Ftb[(u * BATCH + b) * FTB_STR + f] = bf16b(acc + bf[u * F_DIM + f]);
}

// Kernel B: one block (256 thr) per pixel, bf16 MFMA.
// B-fragments (W1) loaded directly from global per wave (R7/R8-verified map):
// lane l, elem j, k-tile kt -> W1[(32kt + 8*(l>>4) + j)*64 + wv*16 + (l&15)].
// Gather path is pure bf16: 2 vector loads per task, direct dword LDS writes.
__global__ __launch_bounds__(256, 4) void pixel_kernel(
    const unsigned short* __restrict__ Ftb, const int* __restrict__ pix_units,
    const float* __restrict__ W1, const float* __restrict__ b1,
    const float* __restrict__ a, const float* __restrict__ Wo,
    const float* __restrict__ bo, float* __restrict__ out,
    const float* __restrict__ S, const float* __restrict__ Wf,
    const float* __restrict__ bf, int Ustar)
{
    const int p = blockIdx.x;
    const int tid = threadIdx.x;
    const int lane = tid & 63;
    const int wv = tid >> 6;
    const int l16 = lane & 15;
    const int l4  = lane >> 4;

    __shared__ unsigned short Gb[BATCH][LSTR];   // 14.5 KB  (Gb[b][k])
    __shared__ float red[4][BATCH];

    // Fixed h-column for this lane's B-fragments:
    const float* __restrict__ w1p =
        W1 + (size_t)p * (KTOT * H_DIM) + (wv << 4) + l16;
    const int krow = 8 * l4;   // fragment k base within a k-tile

    // ---- 1) W1 B-frag loads, chunk 1 (k-tiles 0..3): 32 independent dwords ----
    float wf0[4][8];
#pragma unroll
    for (int kt = 0; kt < 4; ++kt)
#pragma unroll
        for (int j = 0; j < 8; ++j)
            wf0[kt][j] = w1p[(size_t)(32 * kt + krow + j) * H_DIM];

    // ---- 2) Gb gather loads (bf16, independent of W1) ----
    uint4 ga[3]; unsigned int gb2[3];
#pragma unroll
    for (int it = 0; it < 3; ++it) {
        int task = tid + it * 256;
        if (task < K_DIM * BATCH) {
            const int b = task & 31;
            const int u = pix_units[p * K_DIM + (task >> 5)];
            if (u < Ustar) {
                const unsigned short* __restrict__ src =
                    Ftb + ((size_t)(u * BATCH + b) * FTB_STR);
                ga[it]  = *(const uint4*)(src);                 // f0..f7
                gb2[it] = *(const unsigned int*)(src + 8);      // f8,f9
            } else {
                const float* __restrict__ sp = S + b * (UNIT_NO * T_DIM) + u * T_DIM;
                const float* __restrict__ wp = Wf + u * (T_DIM * F_DIM);
                float g[10];
#pragma unroll
                for (int ff = 0; ff < F_DIM; ++ff) {
                    float acc = bf[u * F_DIM + ff];
#pragma unroll
                    for (int t = 0; t < T_DIM; ++t)
                        acc = fmaf(sp[t], wp[t * F_DIM + ff], acc);
                    g[ff] = acc;
                }
                ga[it].x = pack2(g[0], g[1]);
                ga[it].y = pack2(g[2], g[3]);
                ga[it].z = pack2(g[4], g[5]);
                ga[it].w = pack2(g[6], g[7]);
                gb2[it]  = pack2(g[8], g[9]);
            }
        }
    }

    // ---- 3) Pack W1 chunk 1 -> bfrag[0..3] ----
    bf16x8 bfrag[7];
#pragma unroll
    for (int kt = 0; kt < 4; ++kt) {
        union { bf16x8 v; unsigned int u[4]; } t_;
        t_.u[0] = pack2(wf0[kt][0], wf0[kt][1]);
        t_.u[1] = pack2(wf0[kt][2], wf0[kt][3]);
        t_.u[2] = pack2(wf0[kt][4], wf0[kt][5]);
        t_.u[3] = pack2(wf0[kt][6], wf0[kt][7]);
        bfrag[kt] = t_.v;
    }

    // ---- 4) W1 B-frag loads, chunk 2 (k-tiles 4..6; kt=6 predicated) ----
    float wf1[3][8];
#pragma unroll
    for (int kt2 = 0; kt2 < 3; ++kt2) {
        const int kt = 4 + kt2;
#pragma unroll
        for (int j = 0; j < 8; ++j) {
            const int k = 32 * kt + krow + j;
            wf1[kt2][j] = (k < KTOT) ? w1p[(size_t)k * H_DIM] : 0.f;
        }
    }

    // ---- 5) Zero Gb k-pad [200,224), write gathered G to LDS (direct copy) ----
    if (tid < BATCH * 6) {                       // 32 rows x 6 uint2
        const int row = tid / 6;
        const int c   = tid - row * 6;
        *(uint2*)(&Gb[row][KTOT + (c << 2)]) = make_uint2(0u, 0u);
    }
#pragma unroll
    for (int it = 0; it < 3; ++it) {
        int task = tid + it * 256;
        if (task < K_DIM * BATCH) {
            const int j = task >> 5;
            const int b = task & 31;
            unsigned int* dst = (unsigned int*)(&Gb[b][j * F_DIM]);  // j*10 even
            dst[0] = ga[it].x;
            dst[1] = ga[it].y;
            dst[2] = ga[it].z;
            dst[3] = ga[it].w;
            dst[4] = gb2[it];
        }
    }

    // ---- 6) Pack W1 chunk 2 ----
#pragma unroll
    for (int kt2 = 0; kt2 < 3; ++kt2) {
        union { bf16x8 v; unsigned int u[4]; } t_;
        t_.u[0] = pack2(wf1[kt2][0], wf1[kt2][1]);
        t_.u[1] = pack2(wf1[kt2][2], wf1[kt2][3]);
        t_.u[2] = pack2(wf1[kt2][4], wf1[kt2][5]);
        t_.u[3] = pack2(wf1[kt2][6], wf1[kt2][7]);
        bfrag[4 + kt2] = t_.v;
    }
    __syncthreads();

    // ---- 7) MFMA: wave wv -> htile wv; btiles 0,1; 7 k-tiles ----
    f32x4 acc0 = {0.f, 0.f, 0.f, 0.f};
    f32x4 acc1 = {0.f, 0.f, 0.f, 0.f};
    const unsigned short* __restrict__ Arow0 = &Gb[l16][krow];
    const unsigned short* __restrict__ Arow1 = &Gb[16 + l16][krow];
#pragma unroll
    for (int kt = 0; kt < KPAD / 32; ++kt) {
        bf16x8 fa0 = *(const bf16x8*)(Arow0 + kt * 32);
        bf16x8 fa1 = *(const bf16x8*)(Arow1 + kt * 32);
        acc0 = __builtin_amdgcn_mfma_f32_16x16x32_bf16(fa0, bfrag[kt], acc0, 0, 0, 0);
        acc1 = __builtin_amdgcn_mfma_f32_16x16x32_bf16(fa1, bfrag[kt], acc1, 0, 0, 0);
    }

    // ---- 8) Epilogue: bias + PReLU + Wo, reduce over h (R7/R8-verified) ----
    const int h = (wv << 4) + l16;
    const float b1v = b1[p * H_DIM + h];
    const float wov = Wo[p * H_DIM + h];
    const float av  = a[p];
    float s0[4], s1[4];
#pragma unroll
    for (int r = 0; r < 4; ++r) {
        float v0 = acc0[r] + b1v; v0 = (v0 >= 0.f) ? v0 : av * v0;
        float v1 = acc1[r] + b1v; v1 = (v1 >= 0.f) ? v1 : av * v1;
        s0[r] = v0 * wov;
        s1[r] = v1 * wov;
    }
#pragma unroll
    for (int off = 1; off < 16; off <<= 1)
#pragma unroll
        for (int r = 0; r < 4; ++r) {
            s0[r] += __shfl_xor(s0[r], off);
            s1[r] += __shfl_xor(s1[r], off);
        }
    if (l16 == 0) {
#pragma unroll
        for (int r = 0; r < 4; ++r) {
            red[wv][(l4 << 2) + r]      = s0[r];   // b = l4*4+r
            red[wv][16 + (l4 << 2) + r] = s1[r];   // b = 16+l4*4+r
        }
    }
    __syncthreads();
    if (tid < BATCH) {
        float v = red[0][tid] + red[1][tid] + red[2][tid] + red[3][tid] + bo[p];
        out[(size_t)tid * P_DIM + p] = v;
    }
}

extern "C" void kernel_launch(void* const* d_in, const int* in_sizes, int n_in,
                              void* d_out, int out_size, void* d_ws, size_t ws_size,
                              hipStream_t stream) {
    const float* S         = (const float*)d_in[0];
    const int*   pix_units = (const int*)d_in[1];
    const float* Wf        = (const float*)d_in[2];
    const float* bf        = (const float*)d_in[3];
    const float* W1        = (const float*)d_in[4];
    const float* b1        = (const float*)d_in[5];
    const float* a         = (const float*)d_in[6];
    const float* Wo        = (const float*)d_in[7];
    const float* bo        = (const float*)d_in[8];
    float* out = (float*)d_out;
    unsigned short* Ftb = (unsigned short*)d_ws;

    // Units whose [32][16] bf16 tile (1 KB) fits in ws_size; rest recomputed in-block.
    int Ustar = (int)(ws_size / (size_t)(BATCH * FTB_STR * sizeof(unsigned short)));
    if (Ustar > UNIT_NO) Ustar = UNIT_NO;

    if (Ustar > 0)
        featurize_kernel<<<Ustar, 320, 0, stream>>>(S, Wf, bf, Ftb);
    pixel_kernel<<<P_DIM, 256, 0, stream>>>(Ftb, pix_units, W1, b1, a, Wo, bo, out,
                                            S, Wf, bf, Ustar);
}

// Round 11
// 50.043 us; speedup vs baseline: 2.2264x; 2.2264x over previous
//
#include <hip/hip_runtime.h>
#include <hip/hip_bf16.h>

#define UNIT_NO 512
#define T_DIM 25
#define K_DIM 20
#define H_DIM 64
#define P_DIM 4096
#define F_DIM 10
#define BATCH 32
#define KTOT (K_DIM * F_DIM)   // 200
#define KPAD 224               // 7 MFMA k-tiles of 32 (Gb tail zeroed)
#define LSTR 232               // Gb row stride (halfwords): 464B -> conflict-light b128 reads
#define FTB_STR 16             // Ftb per-(u,b) stride in halfwords (10 used + 6 pad) = 32B

typedef short bf16x8 __attribute__((ext_vector_type(8)));
typedef float f32x4 __attribute__((ext_vector_type(4)));

__device__ inline unsigned short bf16b(float x) {
    __hip_bfloat16 h = __float2bfloat16(x);   // RNE
    return *(unsigned short*)&h;
}
__device__ inline unsigned int pack2(float lo, float hi) {
    return (unsigned int)bf16b(lo) | ((unsigned int)bf16b(hi) << 16);
}

// Kernel A: per-unit featurize for units [0, grid), output bf16.
// Ftb[u][b][16] halfwords (f contiguous, 32B per (u,b), pad zeroed).
// Rounding to bf16 here is numerically identical to rounding at gather time.
__global__ __launch_bounds__(320) void featurize_kernel(
    const float* __restrict__ S, const float* __restrict__ Wf,
    const float* __restrict__ bf, unsigned short* __restrict__ Ftb)
{
    const int u = blockIdx.x;
    __shared__ float Ws[T_DIM * F_DIM];   // [t][f]
    __shared__ float Ss[BATCH * T_DIM];   // [b][t]
    const int tid = threadIdx.x;
    for (int i = tid; i < T_DIM * F_DIM; i += 320)
        Ws[i] = Wf[u * (T_DIM * F_DIM) + i];
    for (int i = tid; i < BATCH * T_DIM; i += 320) {
        int b = i / T_DIM;
        int t = i - b * T_DIM;
        Ss[i] = S[b * (UNIT_NO * T_DIM) + u * T_DIM + t];
    }
    // zero the f-pad [10,16) for all 32 b: 192 slots
    if (tid < 192) {
        int b  = tid / 6;
        int fz = 10 + (tid - b * 6);
        Ftb[(u * BATCH + b) * FTB_STR + fz] = 0;
    }
    __syncthreads();
    const int b = tid / F_DIM;    // 0..31
    const int f = tid - b * F_DIM;
    float acc = 0.f;
#pragma unroll
    for (int t = 0; t < T_DIM; ++t)
        acc = fmaf(Ss[b * T_DIM + t], Ws[t * F_DIM + f], acc);
    Ftb[(u * BATCH + b) * FTB_STR + f] = bf16b(acc + bf[u * F_DIM + f]);
}

// ---------------------------------------------------------------------------
// FAST pixel kernel: used when the whole feature table fits in d_ws
// (Ustar == UNIT_NO). NO fallback branch -> low, well-behaved VGPR pressure.
// One block (256 thr) per pixel, bf16 MFMA.
// B-fragments (W1) loaded directly from global per wave (R7/R8-verified map):
// lane l, elem j, k-tile kt -> W1[(32kt + 8*(l>>4) + j)*64 + wv*16 + (l&15)].
// ---------------------------------------------------------------------------
__global__ __launch_bounds__(256, 4) void pixel_fast_kernel(
    const unsigned short* __restrict__ Ftb, const int* __restrict__ pix_units,
    const float* __restrict__ W1, const float* __restrict__ b1,
    const float* __restrict__ a, const float* __restrict__ Wo,
    const float* __restrict__ bo, float* __restrict__ out)
{
    const int p = blockIdx.x;
    const int tid = threadIdx.x;
    const int lane = tid & 63;
    const int wv = tid >> 6;
    const int l16 = lane & 15;
    const int l4  = lane >> 4;

    __shared__ unsigned short Gb[BATCH][LSTR];   // 14.5 KB  (Gb[b][k])
    __shared__ float red[4][BATCH];

    const float* __restrict__ w1p =
        W1 + (size_t)p * (KTOT * H_DIM) + (wv << 4) + l16;
    const int krow = 8 * l4;   // fragment k base within a k-tile

    // ---- 1) W1 B-frag loads, chunk 1 (k-tiles 0..3): 32 independent dwords ----
    float wf0[4][8];
#pragma unroll
    for (int kt = 0; kt < 4; ++kt)
#pragma unroll
        for (int j = 0; j < 8; ++j)
            wf0[kt][j] = w1p[(size_t)(32 * kt + krow + j) * H_DIM];

    // ---- 2) Gb gather loads (bf16, independent of W1) ----
    uint4 ga[3]; unsigned int gb2[3];
#pragma unroll
    for (int it = 0; it < 3; ++it) {
        int task = tid + it * 256;
        if (task < K_DIM * BATCH) {
            const int b = task & 31;
            const int u = pix_units[p * K_DIM + (task >> 5)];
            const unsigned short* __restrict__ src =
                Ftb + ((size_t)(u * BATCH + b) * FTB_STR);
            ga[it]  = *(const uint4*)(src);                 // f0..f7
            gb2[it] = *(const unsigned int*)(src + 8);      // f8,f9
        }
    }

    // ---- 3) Pack W1 chunk 1 -> bfrag[0..3] (frees wf0) ----
    bf16x8 bfrag[7];
#pragma unroll
    for (int kt = 0; kt < 4; ++kt) {
        union { bf16x8 v; unsigned int u[4]; } t_;
        t_.u[0] = pack2(wf0[kt][0], wf0[kt][1]);
        t_.u[1] = pack2(wf0[kt][2], wf0[kt][3]);
        t_.u[2] = pack2(wf0[kt][4], wf0[kt][5]);
        t_.u[3] = pack2(wf0[kt][6], wf0[kt][7]);
        bfrag[kt] = t_.v;
    }

    // ---- 4) W1 B-frag loads, chunk 2 (k-tiles 4..6; k>=200 -> 0) ----
    float wf1[3][8];
#pragma unroll
    for (int kt2 = 0; kt2 < 3; ++kt2) {
        const int kt = 4 + kt2;
#pragma unroll
        for (int j = 0; j < 8; ++j) {
            const int k = 32 * kt + krow + j;
            wf1[kt2][j] = (k < KTOT) ? w1p[(size_t)k * H_DIM] : 0.f;
        }
    }

    // ---- 5) Zero Gb k-pad [200,224), write gathered G to LDS (direct copy) ----
    if (tid < BATCH * 6) {                       // 32 rows x 6 uint2
        const int row = tid / 6;
        const int c   = tid - row * 6;
        *(uint2*)(&Gb[row][KTOT + (c << 2)]) = make_uint2(0u, 0u);
    }
#pragma unroll
    for (int it = 0; it < 3; ++it) {
        int task = tid + it * 256;
        if (task < K_DIM * BATCH) {
            const int j = task >> 5;
            const int b = task & 31;
            unsigned int* dst = (unsigned int*)(&Gb[b][j * F_DIM]);  // j*10 even
            dst[0] = ga[it].x;
            dst[1] = ga[it].y;
            dst[2] = ga[it].z;
            dst[3] = ga[it].w;
            dst[4] = gb2[it];
        }
    }

    // ---- 6) Pack W1 chunk 2 ----
#pragma unroll
    for (int kt2 = 0; kt2 < 3; ++kt2) {
        union { bf16x8 v; unsigned int u[4]; } t_;
        t_.u[0] = pack2(wf1[kt2][0], wf1[kt2][1]);
        t_.u[1] = pack2(wf1[kt2][2], wf1[kt2][3]);
        t_.u[2] = pack2(wf1[kt2][4], wf1[kt2][5]);
        t_.u[3] = pack2(wf1[kt2][6], wf1[kt2][7]);
        bfrag[4 + kt2] = t_.v;
    }
    __syncthreads();

    // ---- 7) MFMA: wave wv -> htile wv; btiles 0,1; 7 k-tiles ----
    f32x4 acc0 = {0.f, 0.f, 0.f, 0.f};
    f32x4 acc1 = {0.f, 0.f, 0.f, 0.f};
    const unsigned short* __restrict__ Arow0 = &Gb[l16][krow];
    const unsigned short* __restrict__ Arow1 = &Gb[16 + l16][krow];
#pragma unroll
    for (int kt = 0; kt < KPAD / 32; ++kt) {
        bf16x8 fa0 = *(const bf16x8*)(Arow0 + kt * 32);
        bf16x8 fa1 = *(const bf16x8*)(Arow1 + kt * 32);
        acc0 = __builtin_amdgcn_mfma_f32_16x16x32_bf16(fa0, bfrag[kt], acc0, 0, 0, 0);
        acc1 = __builtin_amdgcn_mfma_f32_16x16x32_bf16(fa1, bfrag[kt], acc1, 0, 0, 0);
    }

    // ---- 8) Epilogue: bias + PReLU + Wo, reduce over h ----
    const int h = (wv << 4) + l16;
    const float b1v = b1[p * H_DIM + h];
    const float wov = Wo[p * H_DIM + h];
    const float av  = a[p];
    float s0[4], s1[4];
#pragma unroll
    for (int r = 0; r < 4; ++r) {
        float v0 = acc0[r] + b1v; v0 = (v0 >= 0.f) ? v0 : av * v0;
        float v1 = acc1[r] + b1v; v1 = (v1 >= 0.f) ? v1 : av * v1;
        s0[r] = v0 * wov;
        s1[r] = v1 * wov;
    }
#pragma unroll
    for (int off = 1; off < 16; off <<= 1)
#pragma unroll
        for (int r = 0; r < 4; ++r) {
            s0[r] += __shfl_xor(s0[r], off);
            s1[r] += __shfl_xor(s1[r], off);
        }
    if (l16 == 0) {
#pragma unroll
        for (int r = 0; r < 4; ++r) {
            red[wv][(l4 << 2) + r]      = s0[r];   // b = l4*4+r
            red[wv][16 + (l4 << 2) + r] = s1[r];   // b = 16+l4*4+r
        }
    }
    __syncthreads();
    if (tid < BATCH) {
        float v = red[0][tid] + red[1][tid] + red[2][tid] + red[3][tid] + bo[p];
        out[(size_t)tid * P_DIM + p] = v;
    }
}

// ---------------------------------------------------------------------------
// SAFE pixel kernel: only launched when ws_size is too small for the full
// feature table (Ustar < UNIT_NO). Contains the in-block recompute fallback.
// ---------------------------------------------------------------------------
__global__ __launch_bounds__(256, 3) void pixel_safe_kernel(
    const unsigned short* __restrict__ Ftb, const int* __restrict__ pix_units,
    const float* __restrict__ W1, const float* __restrict__ b1,
    const float* __restrict__ a, const float* __restrict__ Wo,
    const float* __restrict__ bo, float* __restrict__ out,
    const float* __restrict__ S, const float* __restrict__ Wf,
    const float* __restrict__ bf, int Ustar)
{
    const int p = blockIdx.x;
    const int tid = threadIdx.x;
    const int lane = tid & 63;
    const int wv = tid >> 6;
    const int l16 = lane & 15;
    const int l4  = lane >> 4;

    __shared__ unsigned short Gb[BATCH][LSTR];
    __shared__ float red[4][BATCH];

    const float* __restrict__ w1p =
        W1 + (size_t)p * (KTOT * H_DIM) + (wv << 4) + l16;
    const int krow = 8 * l4;

    // Gather (with fallback recompute), then LDS.
    uint4 ga[3]; unsigned int gb2[3];
#pragma unroll
    for (int it = 0; it < 3; ++it) {
        int task = tid + it * 256;
        if (task < K_DIM * BATCH) {
            const int b = task & 31;
            const int u = pix_units[p * K_DIM + (task >> 5)];
            if (u < Ustar) {
                const unsigned short* __restrict__ src =
                    Ftb + ((size_t)(u * BATCH + b) * FTB_STR);
                ga[it]  = *(const uint4*)(src);
                gb2[it] = *(const unsigned int*)(src + 8);
            } else {
                const float* __restrict__ sp = S + b * (UNIT_NO * T_DIM) + u * T_DIM;
                const float* __restrict__ wp = Wf + u * (T_DIM * F_DIM);
                float g[10];
#pragma unroll
                for (int ff = 0; ff < F_DIM; ++ff) {
                    float acc = bf[u * F_DIM + ff];
#pragma unroll
                    for (int t = 0; t < T_DIM; ++t)
                        acc = fmaf(sp[t], wp[t * F_DIM + ff], acc);
                    g[ff] = acc;
                }
                ga[it].x = pack2(g[0], g[1]);
                ga[it].y = pack2(g[2], g[3]);
                ga[it].z = pack2(g[4], g[5]);
                ga[it].w = pack2(g[6], g[7]);
                gb2[it]  = pack2(g[8], g[9]);
            }
        }
    }
    if (tid < BATCH * 6) {
        const int row = tid / 6;
        const int c   = tid - row * 6;
        *(uint2*)(&Gb[row][KTOT + (c << 2)]) = make_uint2(0u, 0u);
    }
#pragma unroll
    for (int it = 0; it < 3; ++it) {
        int task = tid + it * 256;
        if (task < K_DIM * BATCH) {
            const int j = task >> 5;
            const int b = task & 31;
            unsigned int* dst = (unsigned int*)(&Gb[b][j * F_DIM]);
            dst[0] = ga[it].x; dst[1] = ga[it].y; dst[2] = ga[it].z;
            dst[3] = ga[it].w; dst[4] = gb2[it];
        }
    }

    // W1 B-fragments (all 7 tiles, simple form — this kernel is the cold path).
    bf16x8 bfrag[7];
#pragma unroll
    for (int kt = 0; kt < 7; ++kt) {
        float wf[8];
#pragma unroll
        for (int j = 0; j < 8; ++j) {
            const int k = 32 * kt + krow + j;
            wf[j] = (k < KTOT) ? w1p[(size_t)k * H_DIM] : 0.f;
        }
        union { bf16x8 v; unsigned int u[4]; } t_;
        t_.u[0] = pack2(wf[0], wf[1]);
        t_.u[1] = pack2(wf[2], wf[3]);
        t_.u[2] = pack2(wf[4], wf[5]);
        t_.u[3] = pack2(wf[6], wf[7]);
        bfrag[kt] = t_.v;
    }
    __syncthreads();

    f32x4 acc0 = {0.f, 0.f, 0.f, 0.f};
    f32x4 acc1 = {0.f, 0.f, 0.f, 0.f};
    const unsigned short* __restrict__ Arow0 = &Gb[l16][krow];
    const unsigned short* __restrict__ Arow1 = &Gb[16 + l16][krow];
#pragma unroll
    for (int kt = 0; kt < KPAD / 32; ++kt) {
        bf16x8 fa0 = *(const bf16x8*)(Arow0 + kt * 32);
        bf16x8 fa1 = *(const bf16x8*)(Arow1 + kt * 32);
        acc0 = __builtin_amdgcn_mfma_f32_16x16x32_bf16(fa0, bfrag[kt], acc0, 0, 0, 0);
        acc1 = __builtin_amdgcn_mfma_f32_16x16x32_bf16(fa1, bfrag[kt], acc1, 0, 0, 0);
    }

    const int h = (wv << 4) + l16;
    const float b1v = b1[p * H_DIM + h];
    const float wov = Wo[p * H_DIM + h];
    const float av  = a[p];
    float s0[4], s1[4];
#pragma unroll
    for (int r = 0; r < 4; ++r) {
        float v0 = acc0[r] + b1v; v0 = (v0 >= 0.f) ? v0 : av * v0;
        float v1 = acc1[r] + b1v; v1 = (v1 >= 0.f) ? v1 : av * v1;
        s0[r] = v0 * wov;
        s1[r] = v1 * wov;
    }
#pragma unroll
    for (int off = 1; off < 16; off <<= 1)
#pragma unroll
        for (int r = 0; r < 4; ++r) {
            s0[r] += __shfl_xor(s0[r], off);
            s1[r] += __shfl_xor(s1[r], off);
        }
    if (l16 == 0) {
#pragma unroll
        for (int r = 0; r < 4; ++r) {
            red[wv][(l4 << 2) + r]      = s0[r];
            red[wv][16 + (l4 << 2) + r] = s1[r];
        }
    }
    __syncthreads();
    if (tid < BATCH) {
        float v = red[0][tid] + red[1][tid] + red[2][tid] + red[3][tid] + bo[p];
        out[(size_t)tid * P_DIM + p] = v;
    }
}

extern "C" void kernel_launch(void* const* d_in, const int* in_sizes, int n_in,
                              void* d_out, int out_size, void* d_ws, size_t ws_size,
                              hipStream_t stream) {
    const float* S         = (const float*)d_in[0];
    const int*   pix_units = (const int*)d_in[1];
    const float* Wf        = (const float*)d_in[2];
    const float* bf        = (const float*)d_in[3];
    const float* W1        = (const float*)d_in[4];
    const float* b1        = (const float*)d_in[5];
    const float* a         = (const float*)d_in[6];
    const float* Wo        = (const float*)d_in[7];
    const float* bo        = (const float*)d_in[8];
    float* out = (float*)d_out;
    unsigned short* Ftb = (unsigned short*)d_ws;

    // Units whose [32][16] bf16 tile (1 KB) fits in ws_size.
    // Deterministic in ws_size only; host-side branch keeps the hot kernel lean.
    int Ustar = (int)(ws_size / (size_t)(BATCH * FTB_STR * sizeof(unsigned short)));
    if (Ustar > UNIT_NO) Ustar = UNIT_NO;

    if (Ustar > 0)
        featurize_kernel<<<Ustar, 320, 0, stream>>>(S, Wf, bf, Ftb);

    if (Ustar >= UNIT_NO) {
        pixel_fast_kernel<<<P_DIM, 256, 0, stream>>>(Ftb, pix_units, W1, b1, a,
                                                     Wo, bo, out);
    } else {
        pixel_safe_kernel<<<P_DIM, 256, 0, stream>>>(Ftb, pix_units, W1, b1, a,
                                                     Wo, bo, out, S, Wf, bf, Ustar);
    }
}

// Round 12
// 46.180 us; speedup vs baseline: 2.4127x; 1.0837x over previous
//
#include <hip/hip_runtime.h>
#include <hip/hip_bf16.h>

#define UNIT_NO 512
#define T_DIM 25
#define K_DIM 20
#define H_DIM 64
#define P_DIM 4096
#define F_DIM 10
#define BATCH 32
#define KTOT (K_DIM * F_DIM)   // 200
#define KPAD 224               // 7 MFMA k-tiles of 32 (Gb tail zeroed)
#define LSTR 232               // Gb row stride (halfwords): 464B -> 2-way-max bank aliasing (free)
#define FTB_STR 16             // Ftb per-(u,b) stride in halfwords (10 used + 6 pad) = 32B

typedef short bf16x8 __attribute__((ext_vector_type(8)));
typedef float f32x4 __attribute__((ext_vector_type(4)));

__device__ inline unsigned short bf16b(float x) {
    __hip_bfloat16 h = __float2bfloat16(x);   // RNE
    return *(unsigned short*)&h;
}
__device__ inline unsigned int pack2(float lo, float hi) {
    return (unsigned int)bf16b(lo) | ((unsigned int)bf16b(hi) << 16);
}

// Kernel A: per-unit featurize for units [0, grid), output bf16.
// Ftb[u][b][16] halfwords (f contiguous, 32B per (u,b), pad zeroed).
// Rounding to bf16 here is numerically identical to rounding at gather time.
__global__ __launch_bounds__(320) void featurize_kernel(
    const float* __restrict__ S, const float* __restrict__ Wf,
    const float* __restrict__ bf, unsigned short* __restrict__ Ftb)
{
    const int u = blockIdx.x;
    __shared__ float Ws[T_DIM * F_DIM];   // [t][f]
    __shared__ float Ss[BATCH * T_DIM];   // [b][t]
    const int tid = threadIdx.x;
    for (int i = tid; i < T_DIM * F_DIM; i += 320)
        Ws[i] = Wf[u * (T_DIM * F_DIM) + i];
    for (int i = tid; i < BATCH * T_DIM; i += 320) {
        int b = i / T_DIM;
        int t = i - b * T_DIM;
        Ss[i] = S[b * (UNIT_NO * T_DIM) + u * T_DIM + t];
    }
    // zero the f-pad [10,16) for all 32 b: 192 slots
    if (tid < 192) {
        int b  = tid / 6;
        int fz = 10 + (tid - b * 6);
        Ftb[(u * BATCH + b) * FTB_STR + fz] = 0;
    }
    __syncthreads();
    const int b = tid / F_DIM;    // 0..31
    const int f = tid - b * F_DIM;
    float acc = 0.f;
#pragma unroll
    for (int t = 0; t < T_DIM; ++t)
        acc = fmaf(Ss[b * T_DIM + t], Ws[t * F_DIM + f], acc);
    Ftb[(u * BATCH + b) * FTB_STR + f] = bf16b(acc + bf[u * F_DIM + f]);
}

// ---------------------------------------------------------------------------
// FAST pixel kernel (Ustar == UNIT_NO): no fallback branch.
// Phase order chosen for LOW PEAK VGPR (gather retired to LDS before the W1
// register pressure builds):
//   gather -> Gb writes -> W1 c1 loads -> W1 c2 loads -> pack c1 -> pack c2
//   -> barrier -> MFMA -> epilogue.
// B-fragment map (R7/R8-verified): lane l, elem j, k-tile kt ->
//   W1[(32kt + 8*(l>>4) + j)*64 + wv*16 + (l&15)].
// __launch_bounds__(256,5): VGPR cap 102 (est. peak ~72-85) -> 5 blocks/CU.
// ---------------------------------------------------------------------------
__global__ __launch_bounds__(256, 5) void pixel_fast_kernel(
    const unsigned short* __restrict__ Ftb, const int* __restrict__ pix_units,
    const float* __restrict__ W1, const float* __restrict__ b1,
    const float* __restrict__ a, const float* __restrict__ Wo,
    const float* __restrict__ bo, float* __restrict__ out)
{
    const int p = blockIdx.x;
    const int tid = threadIdx.x;
    const int lane = tid & 63;
    const int wv = tid >> 6;
    const int l16 = lane & 15;
    const int l4  = lane >> 4;

    __shared__ unsigned short Gb[BATCH][LSTR];   // 14.5 KB  (Gb[b][k])
    __shared__ float red[4][BATCH];

    const float* __restrict__ w1p =
        W1 + (size_t)p * (KTOT * H_DIM) + (wv << 4) + l16;
    const int krow = 8 * l4;   // fragment k base within a k-tile

    // ---- 1) Gather loads (bf16, small register footprint) ----
    uint4 ga[3]; unsigned int gb2[3];
#pragma unroll
    for (int it = 0; it < 3; ++it) {
        const int task = tid + it * 256;
        if (it < 2 || tid < (K_DIM * BATCH - 512)) {
            const int b = task & 31;
            const int u = pix_units[p * K_DIM + (task >> 5)];
            const unsigned short* __restrict__ src =
                Ftb + ((size_t)(u * BATCH + b) * FTB_STR);
            ga[it]  = *(const uint4*)(src);                 // f0..f7
            gb2[it] = *(const unsigned int*)(src + 8);      // f8,f9
        }
    }

    // ---- 2) Zero Gb k-pad [200,224) + write gathered G to LDS (retires ga) ----
    if (tid < BATCH * 6) {                       // 32 rows x 6 uint2
        const int row = tid / 6;
        const int c   = tid - row * 6;
        *(uint2*)(&Gb[row][KTOT + (c << 2)]) = make_uint2(0u, 0u);
    }
#pragma unroll
    for (int it = 0; it < 3; ++it) {
        const int task = tid + it * 256;
        if (it < 2 || tid < (K_DIM * BATCH - 512)) {
            const int j = task >> 5;
            const int b = task & 31;
            unsigned int* dst = (unsigned int*)(&Gb[b][j * F_DIM]);  // j*10 even
            dst[0] = ga[it].x;
            dst[1] = ga[it].y;
            dst[2] = ga[it].z;
            dst[3] = ga[it].w;
            dst[4] = gb2[it];
        }
    }

    // ---- 3) W1 B-frag loads, chunk 1 (k-tiles 0..3): 32 independent dwords ----
    float wf0[4][8];
#pragma unroll
    for (int kt = 0; kt < 4; ++kt)
#pragma unroll
        for (int j = 0; j < 8; ++j)
            wf0[kt][j] = w1p[(size_t)(32 * kt + krow + j) * H_DIM];

    // ---- 4) W1 B-frag loads, chunk 2 (k-tiles 4..6; k>=200 -> 0) ----
    float wf1[3][8];
#pragma unroll
    for (int kt2 = 0; kt2 < 3; ++kt2) {
        const int kt = 4 + kt2;
#pragma unroll
        for (int j = 0; j < 8; ++j) {
            const int k = 32 * kt + krow + j;
            wf1[kt2][j] = (k < KTOT) ? w1p[(size_t)k * H_DIM] : 0.f;
        }
    }

    // ---- 5) Pack chunk 1 -> bfrag[0..3] (retires wf0) ----
    bf16x8 bfrag[7];
#pragma unroll
    for (int kt = 0; kt < 4; ++kt) {
        union { bf16x8 v; unsigned int u[4]; } t_;
        t_.u[0] = pack2(wf0[kt][0], wf0[kt][1]);
        t_.u[1] = pack2(wf0[kt][2], wf0[kt][3]);
        t_.u[2] = pack2(wf0[kt][4], wf0[kt][5]);
        t_.u[3] = pack2(wf0[kt][6], wf0[kt][7]);
        bfrag[kt] = t_.v;
    }

    // ---- 6) Pack chunk 2 -> bfrag[4..6] (retires wf1) ----
#pragma unroll
    for (int kt2 = 0; kt2 < 3; ++kt2) {
        union { bf16x8 v; unsigned int u[4]; } t_;
        t_.u[0] = pack2(wf1[kt2][0], wf1[kt2][1]);
        t_.u[1] = pack2(wf1[kt2][2], wf1[kt2][3]);
        t_.u[2] = pack2(wf1[kt2][4], wf1[kt2][5]);
        t_.u[3] = pack2(wf1[kt2][6], wf1[kt2][7]);
        bfrag[4 + kt2] = t_.v;
    }
    __syncthreads();

    // ---- 7) MFMA: wave wv -> htile wv; btiles 0,1; 7 k-tiles ----
    f32x4 acc0 = {0.f, 0.f, 0.f, 0.f};
    f32x4 acc1 = {0.f, 0.f, 0.f, 0.f};
    const unsigned short* __restrict__ Arow0 = &Gb[l16][krow];
    const unsigned short* __restrict__ Arow1 = &Gb[16 + l16][krow];
#pragma unroll
    for (int kt = 0; kt < KPAD / 32; ++kt) {
        bf16x8 fa0 = *(const bf16x8*)(Arow0 + kt * 32);
        bf16x8 fa1 = *(const bf16x8*)(Arow1 + kt * 32);
        acc0 = __builtin_amdgcn_mfma_f32_16x16x32_bf16(fa0, bfrag[kt], acc0, 0, 0, 0);
        acc1 = __builtin_amdgcn_mfma_f32_16x16x32_bf16(fa1, bfrag[kt], acc1, 0, 0, 0);
    }

    // ---- 8) Epilogue: bias + PReLU + Wo, reduce over h ----
    const int h = (wv << 4) + l16;
    const float b1v = b1[p * H_DIM + h];
    const float wov = Wo[p * H_DIM + h];
    const float av  = a[p];
    float s0[4], s1[4];
#pragma unroll
    for (int r = 0; r < 4; ++r) {
        float v0 = acc0[r] + b1v; v0 = (v0 >= 0.f) ? v0 : av * v0;
        float v1 = acc1[r] + b1v; v1 = (v1 >= 0.f) ? v1 : av * v1;
        s0[r] = v0 * wov;
        s1[r] = v1 * wov;
    }
#pragma unroll
    for (int off = 1; off < 16; off <<= 1)
#pragma unroll
        for (int r = 0; r < 4; ++r) {
            s0[r] += __shfl_xor(s0[r], off);
            s1[r] += __shfl_xor(s1[r], off);
        }
    if (l16 == 0) {
#pragma unroll
        for (int r = 0; r < 4; ++r) {
            red[wv][(l4 << 2) + r]      = s0[r];   // b = l4*4+r
            red[wv][16 + (l4 << 2) + r] = s1[r];   // b = 16+l4*4+r
        }
    }
    __syncthreads();
    if (tid < BATCH) {
        float v = red[0][tid] + red[1][tid] + red[2][tid] + red[3][tid] + bo[p];
        out[(size_t)tid * P_DIM + p] = v;
    }
}

// ---------------------------------------------------------------------------
// SAFE pixel kernel: only launched when ws_size is too small for the full
// feature table (Ustar < UNIT_NO). Contains the in-block recompute fallback.
// ---------------------------------------------------------------------------
__global__ __launch_bounds__(256, 3) void pixel_safe_kernel(
    const unsigned short* __restrict__ Ftb, const int* __restrict__ pix_units,
    const float* __restrict__ W1, const float* __restrict__ b1,
    const float* __restrict__ a, const float* __restrict__ Wo,
    const float* __restrict__ bo, float* __restrict__ out,
    const float* __restrict__ S, const float* __restrict__ Wf,
    const float* __restrict__ bf, int Ustar)
{
    const int p = blockIdx.x;
    const int tid = threadIdx.x;
    const int lane = tid & 63;
    const int wv = tid >> 6;
    const int l16 = lane & 15;
    const int l4  = lane >> 4;

    __shared__ unsigned short Gb[BATCH][LSTR];
    __shared__ float red[4][BATCH];

    const float* __restrict__ w1p =
        W1 + (size_t)p * (KTOT * H_DIM) + (wv << 4) + l16;
    const int krow = 8 * l4;

    uint4 ga[3]; unsigned int gb2[3];
#pragma unroll
    for (int it = 0; it < 3; ++it) {
        int task = tid + it * 256;
        if (task < K_DIM * BATCH) {
            const int b = task & 31;
            const int u = pix_units[p * K_DIM + (task >> 5)];
            if (u < Ustar) {
                const unsigned short* __restrict__ src =
                    Ftb + ((size_t)(u * BATCH + b) * FTB_STR);
                ga[it]  = *(const uint4*)(src);
                gb2[it] = *(const unsigned int*)(src + 8);
            } else {
                const float* __restrict__ sp = S + b * (UNIT_NO * T_DIM) + u * T_DIM;
                const float* __restrict__ wp = Wf + u * (T_DIM * F_DIM);
                float g[10];
#pragma unroll
                for (int ff = 0; ff < F_DIM; ++ff) {
                    float acc = bf[u * F_DIM + ff];
#pragma unroll
                    for (int t = 0; t < T_DIM; ++t)
                        acc = fmaf(sp[t], wp[t * F_DIM + ff], acc);
                    g[ff] = acc;
                }
                ga[it].x = pack2(g[0], g[1]);
                ga[it].y = pack2(g[2], g[3]);
                ga[it].z = pack2(g[4], g[5]);
                ga[it].w = pack2(g[6], g[7]);
                gb2[it]  = pack2(g[8], g[9]);
            }
        }
    }
    if (tid < BATCH * 6) {
        const int row = tid / 6;
        const int c   = tid - row * 6;
        *(uint2*)(&Gb[row][KTOT + (c << 2)]) = make_uint2(0u, 0u);
    }
#pragma unroll
    for (int it = 0; it < 3; ++it) {
        int task = tid + it * 256;
        if (task < K_DIM * BATCH) {
            const int j = task >> 5;
            const int b = task & 31;
            unsigned int* dst = (unsigned int*)(&Gb[b][j * F_DIM]);
            dst[0] = ga[it].x; dst[1] = ga[it].y; dst[2] = ga[it].z;
            dst[3] = ga[it].w; dst[4] = gb2[it];
        }
    }

    bf16x8 bfrag[7];
#pragma unroll
    for (int kt = 0; kt < 7; ++kt) {
        float wf[8];
#pragma unroll
        for (int j = 0; j < 8; ++j) {
            const int k = 32 * kt + krow + j;
            wf[j] = (k < KTOT) ? w1p[(size_t)k * H_DIM] : 0.f;
        }
        union { bf16x8 v; unsigned int u[4]; } t_;
        t_.u[0] = pack2(wf[0], wf[1]);
        t_.u[1] = pack2(wf[2], wf[3]);
        t_.u[2] = pack2(wf[4], wf[5]);
        t_.u[3] = pack2(wf[6], wf[7]);
        bfrag[kt] = t_.v;
    }
    __syncthreads();

    f32x4 acc0 = {0.f, 0.f, 0.f, 0.f};
    f32x4 acc1 = {0.f, 0.f, 0.f, 0.f};
    const unsigned short* __restrict__ Arow0 = &Gb[l16][krow];
    const unsigned short* __restrict__ Arow1 = &Gb[16 + l16][krow];
#pragma unroll
    for (int kt = 0; kt < KPAD / 32; ++kt) {
        bf16x8 fa0 = *(const bf16x8*)(Arow0 + kt * 32);
        bf16x8 fa1 = *(const bf16x8*)(Arow1 + kt * 32);
        acc0 = __builtin_amdgcn_mfma_f32_16x16x32_bf16(fa0, bfrag[kt], acc0, 0, 0, 0);
        acc1 = __builtin_amdgcn_mfma_f32_16x16x32_bf16(fa1, bfrag[kt], acc1, 0, 0, 0);
    }

    const int h = (wv << 4) + l16;
    const float b1v = b1[p * H_DIM + h];
    const float wov = Wo[p * H_DIM + h];
    const float av  = a[p];
    float s0[4], s1[4];
#pragma unroll
    for (int r = 0; r < 4; ++r) {
        float v0 = acc0[r] + b1v; v0 = (v0 >= 0.f) ? v0 : av * v0;
        float v1 = acc1[r] + b1v; v1 = (v1 >= 0.f) ? v1 : av * v1;
        s0[r] = v0 * wov;
        s1[r] = v1 * wov;
    }
#pragma unroll
    for (int off = 1; off < 16; off <<= 1)
#pragma unroll
        for (int r = 0; r < 4; ++r) {
            s0[r] += __shfl_xor(s0[r], off);
            s1[r] += __shfl_xor(s1[r], off);
        }
    if (l16 == 0) {
#pragma unroll
        for (int r = 0; r < 4; ++r) {
            red[wv][(l4 << 2) + r]      = s0[r];
            red[wv][16 + (l4 << 2) + r] = s1[r];
        }
    }
    __syncthreads();
    if (tid < BATCH) {
        float v = red[0][tid] + red[1][tid] + red[2][tid] + red[3][tid] + bo[p];
        out[(size_t)tid * P_DIM + p] = v;
    }
}

extern "C" void kernel_launch(void* const* d_in, const int* in_sizes, int n_in,
                              void* d_out, int out_size, void* d_ws, size_t ws_size,
                              hipStream_t stream) {
    const float* S         = (const float*)d_in[0];
    const int*   pix_units = (const int*)d_in[1];
    const float* Wf        = (const float*)d_in[2];
    const float* bf        = (const float*)d_in[3];
    const float* W1        = (const float*)d_in[4];
    const float* b1        = (const float*)d_in[5];
    const float* a         = (const float*)d_in[6];
    const float* Wo        = (const float*)d_in[7];
    const float* bo        = (const float*)d_in[8];
    float* out = (float*)d_out;
    unsigned short* Ftb = (unsigned short*)d_ws;

    // Units whose [32][16] bf16 tile (1 KB) fits in ws_size.
    // Deterministic in ws_size only; host-side branch keeps the hot kernel lean.
    int Ustar = (int)(ws_size / (size_t)(BATCH * FTB_STR * sizeof(unsigned short)));
    if (Ustar > UNIT_NO) Ustar = UNIT_NO;

    if (Ustar > 0)
        featurize_kernel<<<Ustar, 320, 0, stream>>>(S, Wf, bf, Ftb);

    if (Ustar >= UNIT_NO) {
        pixel_fast_kernel<<<P_DIM, 256, 0, stream>>>(Ftb, pix_units, W1, b1, a,
                                                     Wo, bo, out);
    } else {
        pixel_safe_kernel<<<P_DIM, 256, 0, stream>>>(Ftb, pix_units, W1, b1, a,
                                                     Wo, bo, out, S, Wf, bf, Ustar);
    }
}